// Round 2
// baseline (345.453 us; speedup 1.0000x reference)
//
#include <hip/hip_runtime.h>
#include <hip/hip_bf16.h>

typedef unsigned short u16;
typedef __attribute__((ext_vector_type(8))) short short8;
typedef __attribute__((ext_vector_type(4))) float f32x4;

#define B_  64
#define T_  512
#define H_  1024
#define U_  1024
#define BT_ (B_*T_)

#define BM 128
#define BN 128
#define BK 32

// async global->LDS, 16B per lane, wave-uniform LDS base (HW adds lane*16)
#define GLL16(gp, lp) __builtin_amdgcn_global_load_lds( \
    (const __attribute__((address_space(1))) void*)(gp), \
    (__attribute__((address_space(3))) void*)(lp), 16, 0, 0)

__device__ __forceinline__ u16 f32_to_bf16(float f) {
  union { float f; unsigned u; } v; v.f = f;
  unsigned r = v.u + 0x7FFFu + ((v.u >> 16) & 1u);
  return (u16)(r >> 16);
}

// ---- enc f32 -> bf16 (33.5M elems, 4/thread) ----
__global__ __launch_bounds__(256) void ba_conv_enc(const float4* __restrict__ in,
                                                   ushort4* __restrict__ out) {
  int i = blockIdx.x * 256 + threadIdx.x;
  float4 v = in[i];
  ushort4 o;
  o.x = f32_to_bf16(v.x);
  o.y = f32_to_bf16(v.y);
  o.z = f32_to_bf16(v.z);
  o.w = f32_to_bf16(v.w);
  out[i] = o;
}

// ---- Wh [H][U] f32 -> WhT [U][H] bf16 (tiled transpose) ----
__global__ __launch_bounds__(256) void ba_conv_whT(const float* __restrict__ wh,
                                                   u16* __restrict__ whT) {
  __shared__ float tile[32][33];
  int tx = threadIdx.x, ty = threadIdx.y;
  int u0 = blockIdx.x * 32, h0 = blockIdx.y * 32;
  #pragma unroll
  for (int i = 0; i < 32; i += 8)
    tile[ty + i][tx] = wh[(long)(h0 + ty + i) * U_ + u0 + tx];
  __syncthreads();
  #pragma unroll
  for (int i = 0; i < 32; i += 8)
    whT[(long)(u0 + ty + i) * H_ + h0 + tx] = f32_to_bf16(tile[tx][ty + i]);
}

// ---- fused GEMM + tanh + dot(Wv) -> score[B*T] ----
// A = enc bf16 [32768][1024] row-major (M x K)
// Bt = WhT bf16 [1024][1024] row-major (N x K)  -> B[k][n] = Bt[n][k]
// grid (256, 2): x = M-tile, y = which half of the 8 n-tiles
__global__ __launch_bounds__(256, 2) void ba_score(
    const u16* __restrict__ A, const u16* __restrict__ Bt,
    const float* __restrict__ bh, const float* __restrict__ wv,
    float* __restrict__ score) {
  __shared__ u16 lA[BM * BK];   // [128][32] bf16, 64B rows
  __shared__ u16 lB[BN * BK];

  const int tid  = threadIdx.x;
  const int wid  = tid >> 6;
  const int lane = tid & 63;
  const int wm = wid >> 1, wn = wid & 1;
  const long row0 = (long)blockIdx.x * BM;

  // staging: 8 x 1KB chunks per tile; wave w stages chunks {2w, 2w+1}
  const int c0 = 2 * wid, c1 = 2 * wid + 1;
  const int lsub = lane >> 2;        // row within chunk (16 rows/chunk)
  const int csub = (lane & 3) * 8;   // bf16 col offset within 32-wide row

  const int fr = lane & 15;          // fragment row/col index
  const int ko = (lane >> 4) * 8;    // k offset within BK=32

  float sloc[4][4];                  // [am][r] per-lane partial score
  #pragma unroll
  for (int i = 0; i < 4; ++i)
    #pragma unroll
    for (int r = 0; r < 4; ++r) sloc[i][r] = 0.f;

  const int ntBase = blockIdx.y * 4;
  for (int nt = ntBase; nt < ntBase + 4; ++nt) {
    const int ncol0 = nt * BN;
    f32x4 acc[4][4];
    #pragma unroll
    for (int i = 0; i < 4; ++i)
      #pragma unroll
      for (int j = 0; j < 4; ++j) acc[i][j] = (f32x4){0.f, 0.f, 0.f, 0.f};

    for (int kt = 0; kt < H_; kt += BK) {
      // stage A tile (8KB) + B tile (8KB)
      GLL16(A + (row0 + 16 * c0 + lsub) * H_ + kt + csub, (char*)lA + c0 * 1024);
      GLL16(A + (row0 + 16 * c1 + lsub) * H_ + kt + csub, (char*)lA + c1 * 1024);
      GLL16(Bt + (long)(ncol0 + 16 * c0 + lsub) * H_ + kt + csub, (char*)lB + c0 * 1024);
      GLL16(Bt + (long)(ncol0 + 16 * c1 + lsub) * H_ + kt + csub, (char*)lB + c1 * 1024);
      __syncthreads();

      short8 av[4], bv[4];
      #pragma unroll
      for (int i = 0; i < 4; ++i) {
        av[i] = *(const short8*)&lA[(wm * 64 + i * 16 + fr) * BK + ko];
        bv[i] = *(const short8*)&lB[(wn * 64 + i * 16 + fr) * BK + ko];
      }
      #pragma unroll
      for (int i = 0; i < 4; ++i)
        #pragma unroll
        for (int j = 0; j < 4; ++j)
          acc[i][j] = __builtin_amdgcn_mfma_f32_16x16x32_bf16(av[i], bv[j], acc[i][j], 0, 0, 0);
      __syncthreads();
    }

    // epilogue: x = D + bh[n]; t = tanh(x); sloc += t * wv[n]
    #pragma unroll
    for (int j = 0; j < 4; ++j) {
      const int n = ncol0 + wn * 64 + j * 16 + fr;
      const float bhn = bh[n];
      const float wvn = wv[n];
      #pragma unroll
      for (int i = 0; i < 4; ++i) {
        #pragma unroll
        for (int r = 0; r < 4; ++r) {
          float x = acc[i][j][r] + bhn;
          float e = __expf(2.f * x);
          float t = 1.f - 2.f / (e + 1.f);
          sloc[i][r] += t * wvn;
        }
      }
    }
  }

  // reduce over the 16-lane n-group, then atomicAdd per m
  #pragma unroll
  for (int i = 0; i < 4; ++i) {
    #pragma unroll
    for (int r = 0; r < 4; ++r) {
      float v = sloc[i][r];
      v += __shfl_xor(v, 1);
      v += __shfl_xor(v, 2);
      v += __shfl_xor(v, 4);
      v += __shfl_xor(v, 8);
      if ((lane & 15) == 0) {
        int m = wm * 64 + i * 16 + (lane >> 4) * 4 + r;
        atomicAdd(&score[row0 + m], v);
      }
    }
  }
}

// ---- softmax over T per batch; grid 64, block 256 (2 elems/thread) ----
__global__ __launch_bounds__(256) void ba_softmax(const float* __restrict__ score,
                                                  float* __restrict__ attn) {
  int b = blockIdx.x, tid = threadIdx.x;
  int lane = tid & 63, wid = tid >> 6;
  const float* s = score + b * T_;
  float v0 = s[tid], v1 = s[tid + 256];
  float m = fmaxf(v0, v1);
  #pragma unroll
  for (int o = 1; o < 64; o <<= 1) m = fmaxf(m, __shfl_xor(m, o));
  __shared__ float redm[4];
  __shared__ float reds[4];
  if (lane == 0) redm[wid] = m;
  __syncthreads();
  m = fmaxf(fmaxf(redm[0], redm[1]), fmaxf(redm[2], redm[3]));
  float e0 = __expf(v0 - m), e1 = __expf(v1 - m);
  float sum = e0 + e1;
  #pragma unroll
  for (int o = 1; o < 64; o <<= 1) sum += __shfl_xor(sum, o);
  if (lane == 0) reds[wid] = sum;
  __syncthreads();
  float tot = reds[0] + reds[1] + reds[2] + reds[3];
  float inv = 1.f / tot;
  attn[b * T_ + tid] = e0 * inv;
  attn[b * T_ + tid + 256] = e1 * inv;
}

// ---- context[b,h] = sum_t attn[b,t] * enc[b,t,h] (f32 enc) ----
__global__ __launch_bounds__(256) void ba_context(const float* __restrict__ enc,
                                                  const float* __restrict__ attn,
                                                  float* __restrict__ ctx) {
  int b = blockIdx.y;
  int h = blockIdx.x * 256 + threadIdx.x;
  const float* e = enc + (long)b * T_ * H_ + h;
  const float* a = attn + b * T_;
  float acc = 0.f;
  #pragma unroll 8
  for (int t = 0; t < T_; ++t) acc = fmaf(a[t], e[(long)t * H_], acc);
  ctx[(long)b * H_ + h] = acc;
}

extern "C" void kernel_launch(void* const* d_in, const int* in_sizes, int n_in,
                              void* d_out, int out_size, void* d_ws, size_t ws_size,
                              hipStream_t stream) {
  // inputs: 0 dec_hidden (unused: softmax shift-invariance), 1 enc_output,
  //         2 Wh, 3 bh, 4 Ws (unused), 5 bs (unused), 6 Wv, 7 bv (unused)
  const float* enc = (const float*)d_in[1];
  const float* Wh  = (const float*)d_in[2];
  const float* bh  = (const float*)d_in[3];
  const float* Wv  = (const float*)d_in[6];

  float* out      = (float*)d_out;
  float* ctx_out  = out;             // [64][1024]
  float* attn_out = out + B_ * H_;   // [64][512]

  char* ws = (char*)d_ws;
  u16*  encb  = (u16*)ws;                                  // 67108864 B
  u16*  whT   = (u16*)(ws + (size_t)67108864);             //  2097152 B
  float* score = (float*)(ws + (size_t)67108864 + 2097152); //  131072 B

  ba_conv_enc<<<BT_ * H_ / 4 / 256, 256, 0, stream>>>((const float4*)enc, (ushort4*)encb);
  ba_conv_whT<<<dim3(U_ / 32, H_ / 32), dim3(32, 8), 0, stream>>>(Wh, whT);
  hipMemsetAsync(score, 0, BT_ * sizeof(float), stream);
  ba_score<<<dim3(BT_ / BM, 2), 256, 0, stream>>>(encb, whT, bh, Wv, score);
  ba_softmax<<<B_, 256, 0, stream>>>(score, attn_out);
  ba_context<<<dim3(H_ / 256, B_), 256, 0, stream>>>(enc, attn_out, ctx_out);
}

// Round 4
// 344.516 us; speedup vs baseline: 1.0027x; 1.0027x over previous
//
#include <hip/hip_runtime.h>
#include <hip/hip_bf16.h>

typedef unsigned short u16;
typedef __attribute__((ext_vector_type(8))) short short8;
typedef __attribute__((ext_vector_type(4))) float f32x4;

#define B_  64
#define T_  512
#define H_  1024
#define U_  1024
#define BT_ (B_*T_)

#define BM 128
#define BN 128
#define BK 32

// async global->LDS, 16B per lane, wave-uniform LDS base (HW adds lane*16)
#define GLL16(gp, lp) __builtin_amdgcn_global_load_lds( \
    (const __attribute__((address_space(1))) void*)(gp), \
    (__attribute__((address_space(3))) void*)(lp), 16, 0, 0)

__device__ __forceinline__ u16 f32_to_bf16(float f) {
  union { float f; unsigned u; } v; v.f = f;
  unsigned r = v.u + 0x7FFFu + ((v.u >> 16) & 1u);
  return (u16)(r >> 16);
}
__device__ __forceinline__ unsigned pack_bf16x2(float lo, float hi) {
  return (unsigned)f32_to_bf16(lo) | ((unsigned)f32_to_bf16(hi) << 16);
}

// ---- enc f32 -> bf16, 8 elems/thread ----
__global__ __launch_bounds__(256) void ba_conv_enc(const float4* __restrict__ in,
                                                   uint4* __restrict__ out) {
  int i = blockIdx.x * 256 + threadIdx.x;
  float4 v0 = in[2 * i], v1 = in[2 * i + 1];
  uint4 o;
  o.x = pack_bf16x2(v0.x, v0.y);
  o.y = pack_bf16x2(v0.z, v0.w);
  o.z = pack_bf16x2(v1.x, v1.y);
  o.w = pack_bf16x2(v1.z, v1.w);
  out[i] = o;
}

// ---- Wh [H][U] f32 -> WhT [U][H] bf16 (tiled transpose) ----
__global__ __launch_bounds__(256) void ba_conv_whT(const float* __restrict__ wh,
                                                   u16* __restrict__ whT) {
  __shared__ float tile[32][33];
  int tx = threadIdx.x, ty = threadIdx.y;
  int u0 = blockIdx.x * 32, h0 = blockIdx.y * 32;
  #pragma unroll
  for (int i = 0; i < 32; i += 8)
    tile[ty + i][tx] = wh[(long)(h0 + ty + i) * U_ + u0 + tx];
  __syncthreads();
  #pragma unroll
  for (int i = 0; i < 32; i += 8)
    whT[(long)(u0 + ty + i) * H_ + h0 + tx] = f32_to_bf16(tile[tx][ty + i]);
}

// ---- fused GEMM + tanh + dot(Wv) -> score[B*T] ----
// A = enc bf16 [32768][1024] (M x K), Bt = WhT bf16 [1024][1024] (N x K)
// grid (256, 8): x = M-tile (128 rows), y = N-tile (128 cols)
// LDS tiles [128][32] bf16 with 16B-slot rotation swizzle:
//   phys_slot(r, logical l) = (l + (r>>1)) & 3
// applied on the GLOBAL source column at stage time (LDS write stays
// linear, as global_load_lds requires) and on the read address.
__global__ __launch_bounds__(256, 4) void ba_score(
    const u16* __restrict__ A, const u16* __restrict__ Bt,
    const float* __restrict__ bh, const float* __restrict__ wv,
    float* __restrict__ score) {
  __shared__ u16 lA[BM * BK];
  __shared__ u16 lB[BN * BK];

  const int tid  = threadIdx.x;
  const int wid  = tid >> 6;
  const int lane = tid & 63;
  const int wm = wid >> 1, wn = wid & 1;
  const long row0  = (long)blockIdx.x * BM;
  const int  ncol0 = blockIdx.y * BN;

  // staging: 8 x 1KB chunks per tile; wave w stages chunks {2w, 2w+1}
  const int c0 = 2 * wid, c1 = 2 * wid + 1;
  const int lsub = lane >> 2;   // row within 16-row chunk
  // lane (phys slot s = lane&3, row rotation (lane>>3)&3) fetches
  // logical slot l = (s - rot) & 3  ->  global bf16 col l*8
  const int csw = (((lane & 3) - ((lane >> 3) & 3)) & 3) * 8;

  const int fr = lane & 15;     // fragment row index
  // read: logical slot c = lane>>4 at row R -> phys slot (c + (R>>1))&3;
  // (R>>1)&3 depends only on fr: ((lane>>1)&3)
  const int pofs = ((((lane >> 4) + ((lane >> 1) & 3)) & 3)) * 8;  // u16 offset

  f32x4 acc[4][4];
  #pragma unroll
  for (int i = 0; i < 4; ++i)
    #pragma unroll
    for (int j = 0; j < 4; ++j) acc[i][j] = (f32x4){0.f, 0.f, 0.f, 0.f};

  for (int kt = 0; kt < H_; kt += BK) {
    GLL16(A + (row0 + 16 * c0 + lsub) * H_ + kt + csw, (char*)lA + c0 * 1024);
    GLL16(A + (row0 + 16 * c1 + lsub) * H_ + kt + csw, (char*)lA + c1 * 1024);
    GLL16(Bt + (long)(ncol0 + 16 * c0 + lsub) * H_ + kt + csw, (char*)lB + c0 * 1024);
    GLL16(Bt + (long)(ncol0 + 16 * c1 + lsub) * H_ + kt + csw, (char*)lB + c1 * 1024);
    __syncthreads();

    short8 av[4], bvv[4];
    #pragma unroll
    for (int i = 0; i < 4; ++i) {
      av[i]  = *(const short8*)&lA[(wm * 64 + i * 16 + fr) * BK + pofs];
      bvv[i] = *(const short8*)&lB[(wn * 64 + i * 16 + fr) * BK + pofs];
    }
    #pragma unroll
    for (int i = 0; i < 4; ++i)
      #pragma unroll
      for (int j = 0; j < 4; ++j)
        acc[i][j] = __builtin_amdgcn_mfma_f32_16x16x32_bf16(av[i], bvv[j], acc[i][j], 0, 0, 0);
    __syncthreads();
  }

  // epilogue: x = D + bh[n]; sloc += tanh(x) * wv[n]; reduce over 16-lane
  // n-group; atomicAdd per output row
  float sloc[4][4];
  #pragma unroll
  for (int i = 0; i < 4; ++i)
    #pragma unroll
    for (int r = 0; r < 4; ++r) sloc[i][r] = 0.f;

  #pragma unroll
  for (int j = 0; j < 4; ++j) {
    const int n = ncol0 + wn * 64 + j * 16 + fr;
    const float bhn = bh[n];
    const float wvn = wv[n];
    #pragma unroll
    for (int i = 0; i < 4; ++i) {
      #pragma unroll
      for (int r = 0; r < 4; ++r) {
        float x = acc[i][j][r] + bhn;
        float e = __expf(2.f * x);
        float t = 1.f - 2.f / (e + 1.f);
        sloc[i][r] += t * wvn;
      }
    }
  }

  #pragma unroll
  for (int i = 0; i < 4; ++i) {
    #pragma unroll
    for (int r = 0; r < 4; ++r) {
      float v = sloc[i][r];
      v += __shfl_xor(v, 1);
      v += __shfl_xor(v, 2);
      v += __shfl_xor(v, 4);
      v += __shfl_xor(v, 8);
      if ((lane & 15) == 0) {
        int m = wm * 64 + i * 16 + (lane >> 4) * 4 + r;
        atomicAdd(&score[row0 + m], v);
      }
    }
  }
}

// ---- softmax over T per batch; grid 64, block 256 (2 elems/thread) ----
__global__ __launch_bounds__(256) void ba_softmax(const float* __restrict__ score,
                                                  float* __restrict__ attn) {
  int b = blockIdx.x, tid = threadIdx.x;
  int lane = tid & 63, wid = tid >> 6;
  const float* s = score + b * T_;
  float v0 = s[tid], v1 = s[tid + 256];
  float m = fmaxf(v0, v1);
  #pragma unroll
  for (int o = 1; o < 64; o <<= 1) m = fmaxf(m, __shfl_xor(m, o));
  __shared__ float redm[4];
  __shared__ float reds[4];
  if (lane == 0) redm[wid] = m;
  __syncthreads();
  m = fmaxf(fmaxf(redm[0], redm[1]), fmaxf(redm[2], redm[3]));
  float e0 = __expf(v0 - m), e1 = __expf(v1 - m);
  float sum = e0 + e1;
  #pragma unroll
  for (int o = 1; o < 64; o <<= 1) sum += __shfl_xor(sum, o);
  if (lane == 0) reds[wid] = sum;
  __syncthreads();
  float tot = reds[0] + reds[1] + reds[2] + reds[3];
  float inv = 1.f / tot;
  attn[b * T_ + tid] = e0 * inv;
  attn[b * T_ + tid + 256] = e1 * inv;
}

// ---- context[b,h] = sum_t attn[b,t]*enc[b,t,h]; grid (64,16), t-chunk 32 ----
__global__ __launch_bounds__(256) void ba_context(const float4* __restrict__ enc4,
                                                  const float* __restrict__ attn,
                                                  float* __restrict__ ctx) {
  int b = blockIdx.x;
  int t0 = blockIdx.y * 32;
  int tid = threadIdx.x;
  const float4* e = enc4 + ((long)b * T_ + t0) * (H_ / 4) + tid;
  const float* a = attn + b * T_ + t0;
  float4 acc = {0.f, 0.f, 0.f, 0.f};
  #pragma unroll 4
  for (int t = 0; t < 32; ++t) {
    float4 v = e[(long)t * (H_ / 4)];
    float at = a[t];
    acc.x = fmaf(at, v.x, acc.x);
    acc.y = fmaf(at, v.y, acc.y);
    acc.z = fmaf(at, v.z, acc.z);
    acc.w = fmaf(at, v.w, acc.w);
  }
  float* c = ctx + b * H_ + tid * 4;
  atomicAdd(c + 0, acc.x);
  atomicAdd(c + 1, acc.y);
  atomicAdd(c + 2, acc.z);
  atomicAdd(c + 3, acc.w);
}

extern "C" void kernel_launch(void* const* d_in, const int* in_sizes, int n_in,
                              void* d_out, int out_size, void* d_ws, size_t ws_size,
                              hipStream_t stream) {
  // inputs: 0 dec_hidden (unused: softmax shift-invariance), 1 enc_output,
  //         2 Wh, 3 bh, 4 Ws (unused), 5 bs (unused), 6 Wv, 7 bv (unused)
  const float* enc = (const float*)d_in[1];
  const float* Wh  = (const float*)d_in[2];
  const float* bh  = (const float*)d_in[3];
  const float* Wv  = (const float*)d_in[6];

  float* out      = (float*)d_out;
  float* ctx_out  = out;             // [64][1024]
  float* attn_out = out + B_ * H_;   // [64][512]

  char* ws = (char*)d_ws;
  u16*  encb   = (u16*)ws;                                   // 67108864 B
  u16*  whT    = (u16*)(ws + (size_t)67108864);              //  2097152 B
  float* score = (float*)(ws + (size_t)67108864 + 2097152);  //   131072 B

  ba_conv_enc<<<BT_ * H_ / 8 / 256, 256, 0, stream>>>((const float4*)enc, (uint4*)encb);
  ba_conv_whT<<<dim3(U_ / 32, H_ / 32), dim3(32, 8), 0, stream>>>(Wh, whT);
  hipMemsetAsync(score, 0, BT_ * sizeof(float), stream);
  hipMemsetAsync(ctx_out, 0, B_ * H_ * sizeof(float), stream);
  ba_score<<<dim3(BT_ / BM, U_ / BN), 256, 0, stream>>>(encb, whT, bh, Wv, score);
  ba_softmax<<<B_, 256, 0, stream>>>(score, attn_out);
  ba_context<<<dim3(B_, 16), 256, 0, stream>>>((const float4*)enc, attn_out, ctx_out);
}

// Round 6
// 328.025 us; speedup vs baseline: 1.0531x; 1.0503x over previous
//
#include <hip/hip_runtime.h>
#include <hip/hip_bf16.h>

typedef unsigned short u16;
typedef __attribute__((ext_vector_type(8))) short short8;
typedef __attribute__((ext_vector_type(4))) float f32x4;

#define B_  64
#define T_  512
#define H_  1024
#define U_  1024
#define BT_ (B_*T_)

#define BM 128
#define BN 128
#define BK 32

// async global->LDS, 16B per lane, wave-uniform LDS base (HW adds lane*16)
#define GLL16(gp, lp) __builtin_amdgcn_global_load_lds( \
    (const __attribute__((address_space(1))) void*)(gp), \
    (__attribute__((address_space(3))) void*)(lp), 16, 0, 0)

__device__ __forceinline__ u16 f32_to_bf16(float f) {
  union { float f; unsigned u; } v; v.f = f;
  unsigned r = v.u + 0x7FFFu + ((v.u >> 16) & 1u);
  return (u16)(r >> 16);
}
__device__ __forceinline__ unsigned pack_bf16x2(float lo, float hi) {
  return (unsigned)f32_to_bf16(lo) | ((unsigned)f32_to_bf16(hi) << 16);
}

// ---- enc f32 -> bf16, 8 elems/thread ----
__global__ __launch_bounds__(256) void ba_conv_enc(const float4* __restrict__ in,
                                                   uint4* __restrict__ out) {
  int i = blockIdx.x * 256 + threadIdx.x;
  float4 v0 = in[2 * i], v1 = in[2 * i + 1];
  uint4 o;
  o.x = pack_bf16x2(v0.x, v0.y);
  o.y = pack_bf16x2(v0.z, v0.w);
  o.z = pack_bf16x2(v1.x, v1.y);
  o.w = pack_bf16x2(v1.z, v1.w);
  out[i] = o;
}

// ---- Wh [H][U] f32 -> WhT [U][H] bf16 (tiled transpose) ----
__global__ __launch_bounds__(256) void ba_conv_whT(const float* __restrict__ wh,
                                                   u16* __restrict__ whT) {
  __shared__ float tile[32][33];
  int tx = threadIdx.x, ty = threadIdx.y;
  int u0 = blockIdx.x * 32, h0 = blockIdx.y * 32;
  #pragma unroll
  for (int i = 0; i < 32; i += 8)
    tile[ty + i][tx] = wh[(long)(h0 + ty + i) * U_ + u0 + tx];
  __syncthreads();
  #pragma unroll
  for (int i = 0; i < 32; i += 8)
    whT[(long)(u0 + ty + i) * H_ + h0 + tx] = f32_to_bf16(tile[tx][ty + i]);
}

// ---- fused GEMM + tanh + dot(Wv) -> score[B*T] ----
// A = enc bf16 [32768][1024] (M x K), Bt = WhT bf16 [1024][1024] (N x K)
// grid (256, 8): x = M-tile (128 rows), y = N-tile (128 cols)
// 2-phase pipeline: stage tile kt+1 into buf[cur^1] at top of iter, compute
// tile kt from buf[cur], ONE __syncthreads per K-step (its implicit
// vmcnt(0) drain lands after the compute phase -> latency hidden).
// LDS tiles [128][32] bf16 with 16B-slot rotation swizzle:
//   phys_slot(r, logical l) = (l + (r>>1)) & 3
// applied on the GLOBAL source column at stage time (LDS write stays
// linear, as global_load_lds requires) and on the read address.
__global__ __launch_bounds__(256, 4) void ba_score(
    const u16* __restrict__ A, const u16* __restrict__ Bt,
    const float* __restrict__ bh, const float* __restrict__ wv,
    float* __restrict__ score) {
  __shared__ u16 lA[2][BM * BK];
  __shared__ u16 lB[2][BN * BK];

  const int tid  = threadIdx.x;
  const int wid  = tid >> 6;
  const int lane = tid & 63;
  const int wm = wid >> 1, wn = wid & 1;
  const long row0  = (long)blockIdx.x * BM;
  const int  ncol0 = blockIdx.y * BN;

  // staging: 8 x 1KB chunks per tile; wave w stages chunks {2w, 2w+1}
  const int c0 = 2 * wid, c1 = 2 * wid + 1;
  const int lsub = lane >> 2;   // row within 16-row chunk
  // lane (phys slot s = lane&3, row rotation (lane>>3)&3) fetches
  // logical slot l = (s - rot) & 3  ->  global bf16 col l*8
  const int csw = (((lane & 3) - ((lane >> 3) & 3)) & 3) * 8;

  const int fr = lane & 15;     // fragment row index
  // read: logical slot c = lane>>4 at row R -> phys slot (c + (R>>1))&3;
  // (R>>1)&3 depends only on fr: ((lane>>1)&3)
  const int pofs = ((((lane >> 4) + ((lane >> 1) & 3)) & 3)) * 8;  // u16 offset

  const u16* gA0 = A + (row0 + 16 * c0 + lsub) * H_ + csw;
  const u16* gA1 = A + (row0 + 16 * c1 + lsub) * H_ + csw;
  const u16* gB0 = Bt + (long)(ncol0 + 16 * c0 + lsub) * H_ + csw;
  const u16* gB1 = Bt + (long)(ncol0 + 16 * c1 + lsub) * H_ + csw;

  f32x4 acc[4][4];
  #pragma unroll
  for (int i = 0; i < 4; ++i)
    #pragma unroll
    for (int j = 0; j < 4; ++j) acc[i][j] = (f32x4){0.f, 0.f, 0.f, 0.f};

  // prologue: stage tile 0 into buf 0
  GLL16(gA0, (char*)lA[0] + c0 * 1024);
  GLL16(gA1, (char*)lA[0] + c1 * 1024);
  GLL16(gB0, (char*)lB[0] + c0 * 1024);
  GLL16(gB1, (char*)lB[0] + c1 * 1024);
  __syncthreads();

  int cur = 0;
  for (int kt = 0; kt < H_; kt += BK) {
    // stage next tile into the other buffer (loads fly during compute)
    if (kt + BK < H_) {
      const int nxt = cur ^ 1;
      GLL16(gA0 + kt + BK, (char*)lA[nxt] + c0 * 1024);
      GLL16(gA1 + kt + BK, (char*)lA[nxt] + c1 * 1024);
      GLL16(gB0 + kt + BK, (char*)lB[nxt] + c0 * 1024);
      GLL16(gB1 + kt + BK, (char*)lB[nxt] + c1 * 1024);
    }

    short8 av[4], bvv[4];
    #pragma unroll
    for (int i = 0; i < 4; ++i) {
      av[i]  = *(const short8*)&lA[cur][(wm * 64 + i * 16 + fr) * BK + pofs];
      bvv[i] = *(const short8*)&lB[cur][(wn * 64 + i * 16 + fr) * BK + pofs];
    }
    #pragma unroll
    for (int i = 0; i < 4; ++i)
      #pragma unroll
      for (int j = 0; j < 4; ++j)
        acc[i][j] = __builtin_amdgcn_mfma_f32_16x16x32_bf16(av[i], bvv[j], acc[i][j], 0, 0, 0);

    // one barrier per K-step: drains this iter's stage (mostly landed) and
    // releases buf[cur] for overwrite next iteration
    __syncthreads();
    cur ^= 1;
  }

  // epilogue: x = D + bh[n]; sloc += tanh(x) * wv[n]; reduce over 16-lane
  // n-group; atomicAdd per output row
  float sloc[4][4];
  #pragma unroll
  for (int i = 0; i < 4; ++i)
    #pragma unroll
    for (int r = 0; r < 4; ++r) sloc[i][r] = 0.f;

  #pragma unroll
  for (int j = 0; j < 4; ++j) {
    const int n = ncol0 + wn * 64 + j * 16 + fr;
    const float bhn = bh[n];
    const float wvn = wv[n];
    #pragma unroll
    for (int i = 0; i < 4; ++i) {
      #pragma unroll
      for (int r = 0; r < 4; ++r) {
        float x = acc[i][j][r] + bhn;
        float e = __expf(2.f * x);
        float t = 1.f - 2.f / (e + 1.f);
        sloc[i][r] += t * wvn;
      }
    }
  }

  #pragma unroll
  for (int i = 0; i < 4; ++i) {
    #pragma unroll
    for (int r = 0; r < 4; ++r) {
      float v = sloc[i][r];
      v += __shfl_xor(v, 1);
      v += __shfl_xor(v, 2);
      v += __shfl_xor(v, 4);
      v += __shfl_xor(v, 8);
      if ((lane & 15) == 0) {
        int m = wm * 64 + i * 16 + (lane >> 4) * 4 + r;
        atomicAdd(&score[row0 + m], v);
      }
    }
  }
}

// ---- softmax over T per batch; grid 64, block 256 (2 elems/thread) ----
__global__ __launch_bounds__(256) void ba_softmax(const float* __restrict__ score,
                                                  float* __restrict__ attn) {
  int b = blockIdx.x, tid = threadIdx.x;
  int lane = tid & 63, wid = tid >> 6;
  const float* s = score + b * T_;
  float v0 = s[tid], v1 = s[tid + 256];
  float m = fmaxf(v0, v1);
  #pragma unroll
  for (int o = 1; o < 64; o <<= 1) m = fmaxf(m, __shfl_xor(m, o));
  __shared__ float redm[4];
  __shared__ float reds[4];
  if (lane == 0) redm[wid] = m;
  __syncthreads();
  m = fmaxf(fmaxf(redm[0], redm[1]), fmaxf(redm[2], redm[3]));
  float e0 = __expf(v0 - m), e1 = __expf(v1 - m);
  float sum = e0 + e1;
  #pragma unroll
  for (int o = 1; o < 64; o <<= 1) sum += __shfl_xor(sum, o);
  if (lane == 0) reds[wid] = sum;
  __syncthreads();
  float tot = reds[0] + reds[1] + reds[2] + reds[3];
  float inv = 1.f / tot;
  attn[b * T_ + tid] = e0 * inv;
  attn[b * T_ + tid + 256] = e1 * inv;
}

// ---- context stage 1: partial[b][c][h] = sum_{t in chunk c} attn*enc ----
// grid (64, 16), block 256; chunk = 32 t's; NO atomics.
__global__ __launch_bounds__(256) void ba_context1(const float4* __restrict__ enc4,
                                                   const float* __restrict__ attn,
                                                   float4* __restrict__ part) {
  int b = blockIdx.x;
  int c = blockIdx.y;
  int tid = threadIdx.x;
  const float4* e = enc4 + ((long)b * T_ + c * 32) * (H_ / 4) + tid;
  const float* a = attn + b * T_ + c * 32;
  float4 acc = {0.f, 0.f, 0.f, 0.f};
  #pragma unroll 4
  for (int t = 0; t < 32; ++t) {
    float4 v = e[(long)t * (H_ / 4)];
    float at = a[t];
    acc.x = fmaf(at, v.x, acc.x);
    acc.y = fmaf(at, v.y, acc.y);
    acc.z = fmaf(at, v.z, acc.z);
    acc.w = fmaf(at, v.w, acc.w);
  }
  part[((long)b * 16 + c) * (H_ / 4) + tid] = acc;
}

// ---- context stage 2: ctx[b][h] = sum_c partial[b][c][h]; grid 64 ----
__global__ __launch_bounds__(256) void ba_context2(const float4* __restrict__ part,
                                                   float4* __restrict__ ctx) {
  int b = blockIdx.x;
  int tid = threadIdx.x;
  const float4* p = part + (long)b * 16 * (H_ / 4) + tid;
  float4 acc = {0.f, 0.f, 0.f, 0.f};
  #pragma unroll
  for (int c = 0; c < 16; ++c) {
    float4 v = p[c * (H_ / 4)];
    acc.x += v.x; acc.y += v.y; acc.z += v.z; acc.w += v.w;
  }
  ctx[b * (H_ / 4) + tid] = acc;
}

extern "C" void kernel_launch(void* const* d_in, const int* in_sizes, int n_in,
                              void* d_out, int out_size, void* d_ws, size_t ws_size,
                              hipStream_t stream) {
  // inputs: 0 dec_hidden (unused: softmax shift-invariance), 1 enc_output,
  //         2 Wh, 3 bh, 4 Ws (unused), 5 bs (unused), 6 Wv, 7 bv (unused)
  const float* enc = (const float*)d_in[1];
  const float* Wh  = (const float*)d_in[2];
  const float* bh  = (const float*)d_in[3];
  const float* Wv  = (const float*)d_in[6];

  float* out      = (float*)d_out;
  float* ctx_out  = out;             // [64][1024]
  float* attn_out = out + B_ * H_;   // [64][512]

  char* ws = (char*)d_ws;
  u16*   encb  = (u16*)ws;                                       // 67108864 B
  u16*   whT   = (u16*)(ws + (size_t)67108864);                  //  2097152 B
  float* score = (float*)(ws + (size_t)67108864 + 2097152);      //   131072 B
  float* part  = (float*)(ws + (size_t)67108864 + 2097152 + 131072); // 4 MB

  ba_conv_enc<<<BT_ * H_ / 8 / 256, 256, 0, stream>>>((const float4*)enc, (uint4*)encb);
  ba_conv_whT<<<dim3(U_ / 32, H_ / 32), dim3(32, 8), 0, stream>>>(Wh, whT);
  hipMemsetAsync(score, 0, BT_ * sizeof(float), stream);
  ba_score<<<dim3(BT_ / BM, U_ / BN), 256, 0, stream>>>(encb, whT, bh, Wv, score);
  ba_softmax<<<B_, 256, 0, stream>>>(score, attn_out);
  ba_context1<<<dim3(B_, 16), 256, 0, stream>>>((const float4*)enc, attn_out, (float4*)part);
  ba_context2<<<B_, 256, 0, stream>>>((const float4*)part, (float4*)ctx_out);
}

// Round 7
// 323.110 us; speedup vs baseline: 1.0691x; 1.0152x over previous
//
#include <hip/hip_runtime.h>
#include <hip/hip_bf16.h>

typedef unsigned short u16;
typedef __attribute__((ext_vector_type(8))) short short8;
typedef __attribute__((ext_vector_type(4))) float f32x4;

#define B_  64
#define T_  512
#define H_  1024
#define U_  1024
#define BT_ (B_*T_)

#define BM 128
#define BN 128
#define BK 32

// async global->LDS, 16B per lane, wave-uniform LDS base (HW adds lane*16)
#define GLL16(gp, lp) __builtin_amdgcn_global_load_lds( \
    (const __attribute__((address_space(1))) void*)(gp), \
    (__attribute__((address_space(3))) void*)(lp), 16, 0, 0)

template<int N>
__device__ __forceinline__ void vwait() {
  asm volatile("s_waitcnt vmcnt(%0)" :: "n"(N) : "memory");
}

__device__ __forceinline__ u16 f32_to_bf16(float f) {
  union { float f; unsigned u; } v; v.f = f;
  unsigned r = v.u + 0x7FFFu + ((v.u >> 16) & 1u);
  return (u16)(r >> 16);
}
__device__ __forceinline__ unsigned pack_bf16x2(float lo, float hi) {
  return (unsigned)f32_to_bf16(lo) | ((unsigned)f32_to_bf16(hi) << 16);
}

// ---- prep: enc f32->bf16 (blocks 0..16383), Wh transpose->bf16 (blocks
// 16384..17407), score zeroing (blocks 0..127 double duty) ----
__global__ __launch_bounds__(256) void ba_prep(const float4* __restrict__ in,
                                               uint4* __restrict__ out,
                                               const float* __restrict__ wh,
                                               u16* __restrict__ whT,
                                               float* __restrict__ score) {
  __shared__ float tile[32][33];
  const int bx = blockIdx.x;
  const int tid = threadIdx.x;
  if (bx < 16384) {
    int i = bx * 256 + tid;
    float4 v0 = in[2 * i], v1 = in[2 * i + 1];
    uint4 o;
    o.x = pack_bf16x2(v0.x, v0.y);
    o.y = pack_bf16x2(v0.z, v0.w);
    o.z = pack_bf16x2(v1.x, v1.y);
    o.w = pack_bf16x2(v1.z, v1.w);
    out[i] = o;
    if (bx < 128) score[bx * 256 + tid] = 0.f;
  } else {
    int wb = bx - 16384;
    int u0 = (wb & 31) * 32, h0 = (wb >> 5) * 32;
    int tx = tid & 31, ty = tid >> 5;  // 32 x 8
    #pragma unroll
    for (int i = 0; i < 32; i += 8)
      tile[ty + i][tx] = wh[(long)(h0 + ty + i) * U_ + u0 + tx];
    __syncthreads();
    #pragma unroll
    for (int i = 0; i < 32; i += 8)
      whT[(long)(u0 + ty + i) * H_ + h0 + tx] = f32_to_bf16(tile[tx][ty + i]);
  }
}

// ---- fused GEMM + tanh + dot(Wv) -> score[B*T] ----
// A = enc bf16 [32768][1024] (M x K), Bt = WhT bf16 [1024][1024] (N x K)
// grid (256, 8): x = M-tile (128 rows), y = N-tile (128 cols)
// 3-buffer depth-2 pipeline with COUNTED vmcnt (T4): tiles s, s+1, s+2 in
// flight; per step wait vmcnt(8) (tile s landed, 8 loads still flying),
// raw s_barrier, compute, barrier, stage tile s+3 into the freed buffer.
// Never drains vmcnt to 0 in the main loop.
// LDS tiles [128][32] bf16 with 16B-slot rotation swizzle:
//   phys_slot(r, logical l) = (l + (r>>1)) & 3
// applied on the GLOBAL source column at stage time (LDS write stays
// linear, as global_load_lds requires) and on the read address.
__global__ __launch_bounds__(256, 3) void ba_score(
    const u16* __restrict__ A, const u16* __restrict__ Bt,
    const float* __restrict__ bh, const float* __restrict__ wv,
    float* __restrict__ score) {
  __shared__ u16 lA[3][BM * BK];
  __shared__ u16 lB[3][BN * BK];

  const int tid  = threadIdx.x;
  const int wid  = tid >> 6;
  const int lane = tid & 63;
  const int wm = wid >> 1, wn = wid & 1;
  const long row0  = (long)blockIdx.x * BM;
  const int  ncol0 = blockIdx.y * BN;

  // staging: 8 x 1KB chunks per tile; wave w stages chunks {2w, 2w+1}
  const int c0 = 2 * wid, c1 = 2 * wid + 1;
  const int lsub = lane >> 2;   // row within 16-row chunk
  const int csw = (((lane & 3) - ((lane >> 3) & 3)) & 3) * 8;

  const int fr = lane & 15;     // fragment row index
  const int pofs = ((((lane >> 4) + ((lane >> 1) & 3)) & 3)) * 8;  // u16 offset

  const u16* gA0 = A + (row0 + 16 * c0 + lsub) * H_ + csw;
  const u16* gA1 = A + (row0 + 16 * c1 + lsub) * H_ + csw;
  const u16* gB0 = Bt + (long)(ncol0 + 16 * c0 + lsub) * H_ + csw;
  const u16* gB1 = Bt + (long)(ncol0 + 16 * c1 + lsub) * H_ + csw;

  f32x4 acc[4][4];
  #pragma unroll
  for (int i = 0; i < 4; ++i)
    #pragma unroll
    for (int j = 0; j < 4; ++j) acc[i][j] = (f32x4){0.f, 0.f, 0.f, 0.f};

#define STAGE(t, b) do { \
    const int _k = (t) * BK; \
    GLL16(gA0 + _k, (char*)lA[b] + c0 * 1024); \
    GLL16(gA1 + _k, (char*)lA[b] + c1 * 1024); \
    GLL16(gB0 + _k, (char*)lB[b] + c0 * 1024); \
    GLL16(gB1 + _k, (char*)lB[b] + c1 * 1024); \
  } while (0)

#define KSTEP(s, bi, WAITN) do { \
    vwait<WAITN>(); \
    __builtin_amdgcn_sched_barrier(0); \
    __builtin_amdgcn_s_barrier(); \
    __builtin_amdgcn_sched_barrier(0); \
    short8 av[4], bvv[4]; \
    _Pragma("unroll") \
    for (int i = 0; i < 4; ++i) { \
      av[i]  = *(const short8*)&lA[bi][(wm * 64 + i * 16 + fr) * BK + pofs]; \
      bvv[i] = *(const short8*)&lB[bi][(wn * 64 + i * 16 + fr) * BK + pofs]; \
    } \
    _Pragma("unroll") \
    for (int i = 0; i < 4; ++i) \
      _Pragma("unroll") \
      for (int j = 0; j < 4; ++j) \
        acc[i][j] = __builtin_amdgcn_mfma_f32_16x16x32_bf16(av[i], bvv[j], acc[i][j], 0, 0, 0); \
    __builtin_amdgcn_sched_barrier(0); \
    __builtin_amdgcn_s_barrier(); \
    __builtin_amdgcn_sched_barrier(0); \
    if ((s) + 3 < 32) STAGE((s) + 3, bi); \
  } while (0)

  // prologue: 3 tiles in flight (12 outstanding loads per wave)
  STAGE(0, 0);
  STAGE(1, 1);
  STAGE(2, 2);

  int bi = 0;
  for (int s = 0; s < 30; ++s) {
    KSTEP(s, bi, 8);
    bi = (bi == 2) ? 0 : bi + 1;
  }
  KSTEP(30, bi, 4);
  bi = (bi == 2) ? 0 : bi + 1;
  KSTEP(31, bi, 0);
#undef KSTEP
#undef STAGE

  // epilogue: x = D + bh[n]; sloc += tanh(x) * wv[n]; reduce over 16-lane
  // n-group; atomicAdd per output row
  float sloc[4][4];
  #pragma unroll
  for (int i = 0; i < 4; ++i)
    #pragma unroll
    for (int r = 0; r < 4; ++r) sloc[i][r] = 0.f;

  #pragma unroll
  for (int j = 0; j < 4; ++j) {
    const int n = ncol0 + wn * 64 + j * 16 + fr;
    const float bhn = bh[n];
    const float wvn = wv[n];
    #pragma unroll
    for (int i = 0; i < 4; ++i) {
      #pragma unroll
      for (int r = 0; r < 4; ++r) {
        float x = acc[i][j][r] + bhn;
        float e = __expf(2.f * x);
        float t = 1.f - 2.f / (e + 1.f);
        sloc[i][r] += t * wvn;
      }
    }
  }

  #pragma unroll
  for (int i = 0; i < 4; ++i) {
    #pragma unroll
    for (int r = 0; r < 4; ++r) {
      float v = sloc[i][r];
      v += __shfl_xor(v, 1);
      v += __shfl_xor(v, 2);
      v += __shfl_xor(v, 4);
      v += __shfl_xor(v, 8);
      if ((lane & 15) == 0) {
        int m = wm * 64 + i * 16 + (lane >> 4) * 4 + r;
        atomicAdd(&score[row0 + m], v);
      }
    }
  }
}

// ---- context stage 1 + fused softmax ----
// grid (64, 16): each block redundantly computes the row softmax stats
// (bitwise identical across blocks), block c==0 writes attn_out, then
// reduces its 32-t chunk of attn*enc into part. NO atomics.
__global__ __launch_bounds__(256) void ba_context1(const float4* __restrict__ enc4,
                                                   const float* __restrict__ score,
                                                   float* __restrict__ attn_out,
                                                   float4* __restrict__ part) {
  __shared__ float redm[4], reds[4];
  __shared__ float atile[32];
  int b = blockIdx.x, c = blockIdx.y, tid = threadIdx.x;
  int lane = tid & 63, wid = tid >> 6;
  const float* s = score + b * T_;
  float v0 = s[tid], v1 = s[tid + 256];
  float m = fmaxf(v0, v1);
  #pragma unroll
  for (int o = 1; o < 64; o <<= 1) m = fmaxf(m, __shfl_xor(m, o));
  if (lane == 0) redm[wid] = m;
  __syncthreads();
  m = fmaxf(fmaxf(redm[0], redm[1]), fmaxf(redm[2], redm[3]));
  float e0 = __expf(v0 - m), e1 = __expf(v1 - m);
  float sum = e0 + e1;
  #pragma unroll
  for (int o = 1; o < 64; o <<= 1) sum += __shfl_xor(sum, o);
  if (lane == 0) reds[wid] = sum;
  __syncthreads();
  float inv = 1.f / (reds[0] + reds[1] + reds[2] + reds[3]);

  if (c == 0) {
    attn_out[b * T_ + tid] = e0 * inv;
    attn_out[b * T_ + tid + 256] = e1 * inv;
  }
  // publish this block's 32 attn values to LDS
  int base = c * 32;
  if (base < 256) {
    if (tid >= base && tid < base + 32) atile[tid - base] = e0 * inv;
  } else {
    int bb = base - 256;
    if (tid >= bb && tid < bb + 32) atile[tid - bb] = e1 * inv;
  }
  __syncthreads();

  const float4* e = enc4 + ((long)b * T_ + base) * (H_ / 4) + tid;
  float4 acc = {0.f, 0.f, 0.f, 0.f};
  #pragma unroll 4
  for (int t = 0; t < 32; ++t) {
    float4 v = e[(long)t * (H_ / 4)];
    float at = atile[t];
    acc.x = fmaf(at, v.x, acc.x);
    acc.y = fmaf(at, v.y, acc.y);
    acc.z = fmaf(at, v.z, acc.z);
    acc.w = fmaf(at, v.w, acc.w);
  }
  part[((long)b * 16 + c) * (H_ / 4) + tid] = acc;
}

// ---- context stage 2: ctx[b][h] = sum_c partial[b][c][h]; grid 64 ----
__global__ __launch_bounds__(256) void ba_context2(const float4* __restrict__ part,
                                                   float4* __restrict__ ctx) {
  int b = blockIdx.x;
  int tid = threadIdx.x;
  const float4* p = part + (long)b * 16 * (H_ / 4) + tid;
  float4 acc = {0.f, 0.f, 0.f, 0.f};
  #pragma unroll
  for (int c = 0; c < 16; ++c) {
    float4 v = p[c * (H_ / 4)];
    acc.x += v.x; acc.y += v.y; acc.z += v.z; acc.w += v.w;
  }
  ctx[b * (H_ / 4) + tid] = acc;
}

extern "C" void kernel_launch(void* const* d_in, const int* in_sizes, int n_in,
                              void* d_out, int out_size, void* d_ws, size_t ws_size,
                              hipStream_t stream) {
  // inputs: 0 dec_hidden (unused: softmax shift-invariance), 1 enc_output,
  //         2 Wh, 3 bh, 4 Ws (unused), 5 bs (unused), 6 Wv, 7 bv (unused)
  const float* enc = (const float*)d_in[1];
  const float* Wh  = (const float*)d_in[2];
  const float* bh  = (const float*)d_in[3];
  const float* Wv  = (const float*)d_in[6];

  float* out      = (float*)d_out;
  float* ctx_out  = out;             // [64][1024]
  float* attn_out = out + B_ * H_;   // [64][512]

  char* ws = (char*)d_ws;
  u16*   encb  = (u16*)ws;                                       // 67108864 B
  u16*   whT   = (u16*)(ws + (size_t)67108864);                  //  2097152 B
  float* score = (float*)(ws + (size_t)67108864 + 2097152);      //   131072 B
  float* part  = (float*)(ws + (size_t)67108864 + 2097152 + 131072); // 4 MB

  ba_prep<<<16384 + 1024, 256, 0, stream>>>((const float4*)enc, (uint4*)encb,
                                            Wh, whT, score);
  ba_score<<<dim3(BT_ / BM, U_ / BN), 256, 0, stream>>>(encb, whT, bh, Wv, score);
  ba_context1<<<dim3(B_, 16), 256, 0, stream>>>((const float4*)enc, score,
                                                attn_out, (float4*)part);
  ba_context2<<<B_, 256, 0, stream>>>((const float4*)part, (float4*)ctx_out);
}

// Round 8
// 323.008 us; speedup vs baseline: 1.0695x; 1.0003x over previous
//
#include <hip/hip_runtime.h>
#include <hip/hip_bf16.h>

typedef unsigned short u16;
typedef __attribute__((ext_vector_type(8))) short short8;
typedef __attribute__((ext_vector_type(4))) float f32x4;

#define B_  64
#define T_  512
#define H_  1024
#define U_  1024
#define BT_ (B_*T_)

#define BM 256
#define BN 256
#define BK 32

// async global->LDS, 16B per lane, wave-uniform LDS base (HW adds lane*16)
#define GLL16(gp, lp) __builtin_amdgcn_global_load_lds( \
    (const __attribute__((address_space(1))) void*)(gp), \
    (__attribute__((address_space(3))) void*)(lp), 16, 0, 0)

template<int N>
__device__ __forceinline__ void vwait() {
  asm volatile("s_waitcnt vmcnt(%0)" :: "n"(N) : "memory");
}

__device__ __forceinline__ u16 f32_to_bf16(float f) {
  union { float f; unsigned u; } v; v.f = f;
  unsigned r = v.u + 0x7FFFu + ((v.u >> 16) & 1u);
  return (u16)(r >> 16);
}
__device__ __forceinline__ unsigned pack_bf16x2(float lo, float hi) {
  return (unsigned)f32_to_bf16(lo) | ((unsigned)f32_to_bf16(hi) << 16);
}

// ---- prep: enc f32->bf16 (blocks 0..16383), Wh transpose->bf16 (blocks
// 16384..17407), score zeroing (blocks 0..127 double duty) ----
__global__ __launch_bounds__(256) void ba_prep(const float4* __restrict__ in,
                                               uint4* __restrict__ out,
                                               const float* __restrict__ wh,
                                               u16* __restrict__ whT,
                                               float* __restrict__ score) {
  __shared__ float tile[32][33];
  const int bx = blockIdx.x;
  const int tid = threadIdx.x;
  if (bx < 16384) {
    int i = bx * 256 + tid;
    float4 v0 = in[2 * i], v1 = in[2 * i + 1];
    uint4 o;
    o.x = pack_bf16x2(v0.x, v0.y);
    o.y = pack_bf16x2(v0.z, v0.w);
    o.z = pack_bf16x2(v1.x, v1.y);
    o.w = pack_bf16x2(v1.z, v1.w);
    out[i] = o;
    if (bx < 128) score[bx * 256 + tid] = 0.f;
  } else {
    int wb = bx - 16384;
    int u0 = (wb & 31) * 32, h0 = (wb >> 5) * 32;
    int tx = tid & 31, ty = tid >> 5;  // 32 x 8
    #pragma unroll
    for (int i = 0; i < 32; i += 8)
      tile[ty + i][tx] = wh[(long)(h0 + ty + i) * U_ + u0 + tx];
    __syncthreads();
    #pragma unroll
    for (int i = 0; i < 32; i += 8)
      whT[(long)(u0 + ty + i) * H_ + h0 + tx] = f32_to_bf16(tile[tx][ty + i]);
  }
}

// ---- fused GEMM + tanh + dot(Wv) -> score[B*T] ----
// A = enc bf16 [32768][1024] (M x K), Bt = WhT bf16 [1024][1024] (N x K)
// grid (128, 4): 256x256 block tile; 512 threads = 8 waves (2 wm x 4 wn),
// wave tile 128x64 (acc[8][4] 16x16 frags).
// Deep pipeline: 4 LDS buffers (one K-tile each, 32 KB), prefetch depth 3
// K-tiles (12 outstanding gload_lds/thread), vmcnt(8) at tile top (never 0
// until tail). ONE s_barrier per K-tile (covers RAW on tile t and WAR on
// the buffer being restaged: all reads of t-1 precede this barrier).
// Per tile, two 16-MFMA phases (m-half quadrants); stage of tile t+3 split
// across the phases; setprio(1) around each MFMA cluster.
// LDS rows are 64B (32 bf16): 16B-slot rotation swizzle
//   phys_slot(r, l) = (l + (r>>1)) & 3
// pre-applied on the GLOBAL source column (LDS write stays linear, as
// global_load_lds requires) and on the read address. Proven 0-conflict.
__global__ __launch_bounds__(512, 2) void ba_score(
    const u16* __restrict__ A, const u16* __restrict__ Bt,
    const float* __restrict__ bh, const float* __restrict__ wv,
    float* __restrict__ score) {
  __shared__ u16 lA[4][BM * BK];   // 4 x 16 KB
  __shared__ u16 lB[4][BN * BK];   // 4 x 16 KB

  const int tid  = threadIdx.x;    // 0..511
  const int wid  = tid >> 6;       // 0..7
  const int lane = tid & 63;
  const int wm = wid >> 2;         // 0..1 -> M half (128 rows)
  const int wn = wid & 3;          // 0..3 -> N quarter (64 cols)
  const long row0  = (long)blockIdx.x * BM;
  const int  ncol0 = blockIdx.y * BN;

  // staging: each issue = 512 thr x 16B = 8 KB = 128 rows of 64B.
  // thread -> row tid>>2, phys slot tid&3; fetch logical (s - rot)&3
  const int srow = tid >> 2;
  const int csw  = (((tid & 3) - ((tid >> 3) & 3)) & 3) * 8;

  const int fr = lane & 15;
  const int pofs = (((lane >> 4) + ((lane >> 1) & 3)) & 3) * 8;  // u16 units
  const int aBase = (wm * 128 + fr) * BK + pofs;  // + mf*512
  const int bBase = (wn * 64  + fr) * BK + pofs;  // + nf*512

  const u16* gA = A  + (row0 + srow) * H_ + csw;
  const u16* gB = Bt + (long)(ncol0 + srow) * H_ + csw;

  f32x4 acc[8][4];
  #pragma unroll
  for (int i = 0; i < 8; ++i)
    #pragma unroll
    for (int j = 0; j < 4; ++j) acc[i][j] = (f32x4){0.f, 0.f, 0.f, 0.f};

#define STAGEF(t_, b_) do { \
    const long _k = (long)(t_) * BK; \
    GLL16(gA + _k,            (char*)lA[b_] + wid * 1024); \
    GLL16(gA + 128 * H_ + _k, (char*)lA[b_] + 8192 + wid * 1024); \
    GLL16(gB + _k,            (char*)lB[b_] + wid * 1024); \
    GLL16(gB + 128 * H_ + _k, (char*)lB[b_] + 8192 + wid * 1024); \
  } while (0)

#define TILE(t_, WAITN, DO_STAGE) do { \
    const int _bt = (t_) & 3; \
    vwait<WAITN>(); \
    __builtin_amdgcn_sched_barrier(0); \
    __builtin_amdgcn_s_barrier(); \
    __builtin_amdgcn_sched_barrier(0); \
    short8 bfrag[4], afrag[4]; \
    _Pragma("unroll") \
    for (int nf = 0; nf < 4; ++nf) \
      bfrag[nf] = *(const short8*)&lB[_bt][bBase + nf * 512]; \
    _Pragma("unroll") \
    for (int mf = 0; mf < 4; ++mf) \
      afrag[mf] = *(const short8*)&lA[_bt][aBase + mf * 512]; \
    if (DO_STAGE) { \
      const long _k = (long)((t_) + 3) * BK; \
      const int _nb = ((t_) + 3) & 3; \
      GLL16(gA + _k,            (char*)lA[_nb] + wid * 1024); \
      GLL16(gA + 128 * H_ + _k, (char*)lA[_nb] + 8192 + wid * 1024); \
    } \
    __builtin_amdgcn_s_setprio(1); \
    _Pragma("unroll") \
    for (int mf = 0; mf < 4; ++mf) \
      _Pragma("unroll") \
      for (int nf = 0; nf < 4; ++nf) \
        acc[mf][nf] = __builtin_amdgcn_mfma_f32_16x16x32_bf16(afrag[mf], bfrag[nf], acc[mf][nf], 0, 0, 0); \
    __builtin_amdgcn_s_setprio(0); \
    _Pragma("unroll") \
    for (int mf = 0; mf < 4; ++mf) \
      afrag[mf] = *(const short8*)&lA[_bt][aBase + (4 + mf) * 512]; \
    if (DO_STAGE) { \
      const long _k = (long)((t_) + 3) * BK; \
      const int _nb = ((t_) + 3) & 3; \
      GLL16(gB + _k,            (char*)lB[_nb] + wid * 1024); \
      GLL16(gB + 128 * H_ + _k, (char*)lB[_nb] + 8192 + wid * 1024); \
    } \
    __builtin_amdgcn_s_setprio(1); \
    _Pragma("unroll") \
    for (int mf = 0; mf < 4; ++mf) \
      _Pragma("unroll") \
      for (int nf = 0; nf < 4; ++nf) \
        acc[4 + mf][nf] = __builtin_amdgcn_mfma_f32_16x16x32_bf16(afrag[mf], bfrag[nf], acc[4 + mf][nf], 0, 0, 0); \
    __builtin_amdgcn_s_setprio(0); \
  } while (0)

  // prologue: 3 K-tiles in flight (12 outstanding loads per thread)
  STAGEF(0, 0);
  STAGEF(1, 1);
  STAGEF(2, 2);

  for (int t = 0; t < 30; ++t) {
    TILE(t, 8, t < 29);   // steady state: wait tile t, 8 loads still flying
  }
  TILE(30, 4, false);
  TILE(31, 0, false);
#undef TILE
#undef STAGEF

  // epilogue: x = D + bh[n]; sloc += tanh(x) * wv[n]; reduce over 16-lane
  // n-group + nf; atomicAdd per output row (4 wn-waves x 4 y-blocks = 16
  // contributors per score element)
  float sloc[8][4];
  #pragma unroll
  for (int mf = 0; mf < 8; ++mf)
    #pragma unroll
    for (int r = 0; r < 4; ++r) sloc[mf][r] = 0.f;

  #pragma unroll
  for (int nf = 0; nf < 4; ++nf) {
    const int n = ncol0 + wn * 64 + nf * 16 + fr;
    const float bhn = bh[n];
    const float wvn = wv[n];
    #pragma unroll
    for (int mf = 0; mf < 8; ++mf) {
      #pragma unroll
      for (int r = 0; r < 4; ++r) {
        float x = acc[mf][nf][r] + bhn;
        float e = __expf(2.f * x);
        sloc[mf][r] += (1.f - 2.f / (e + 1.f)) * wvn;
      }
    }
  }

  #pragma unroll
  for (int mf = 0; mf < 8; ++mf) {
    #pragma unroll
    for (int r = 0; r < 4; ++r) {
      float v = sloc[mf][r];
      v += __shfl_xor(v, 1);
      v += __shfl_xor(v, 2);
      v += __shfl_xor(v, 4);
      v += __shfl_xor(v, 8);
      if ((lane & 15) == 0) {
        long m = row0 + wm * 128 + mf * 16 + (lane >> 4) * 4 + r;
        atomicAdd(&score[m], v);
      }
    }
  }
}

// ---- context stage 1 + fused softmax ----
// grid (64, 16): each block redundantly computes the row softmax stats
// (bitwise identical across blocks), block c==0 writes attn_out, then
// reduces its 32-t chunk of attn*enc into part. NO atomics.
__global__ __launch_bounds__(256) void ba_context1(const float4* __restrict__ enc4,
                                                   const float* __restrict__ score,
                                                   float* __restrict__ attn_out,
                                                   float4* __restrict__ part) {
  __shared__ float redm[4], reds[4];
  __shared__ float atile[32];
  int b = blockIdx.x, c = blockIdx.y, tid = threadIdx.x;
  int lane = tid & 63, wid = tid >> 6;
  const float* s = score + b * T_;
  float v0 = s[tid], v1 = s[tid + 256];
  float m = fmaxf(v0, v1);
  #pragma unroll
  for (int o = 1; o < 64; o <<= 1) m = fmaxf(m, __shfl_xor(m, o));
  if (lane == 0) redm[wid] = m;
  __syncthreads();
  m = fmaxf(fmaxf(redm[0], redm[1]), fmaxf(redm[2], redm[3]));
  float e0 = __expf(v0 - m), e1 = __expf(v1 - m);
  float sum = e0 + e1;
  #pragma unroll
  for (int o = 1; o < 64; o <<= 1) sum += __shfl_xor(sum, o);
  if (lane == 0) reds[wid] = sum;
  __syncthreads();
  float inv = 1.f / (reds[0] + reds[1] + reds[2] + reds[3]);

  if (c == 0) {
    attn_out[b * T_ + tid] = e0 * inv;
    attn_out[b * T_ + tid + 256] = e1 * inv;
  }
  // publish this block's 32 attn values to LDS
  int base = c * 32;
  if (base < 256) {
    if (tid >= base && tid < base + 32) atile[tid - base] = e0 * inv;
  } else {
    int bb = base - 256;
    if (tid >= bb && tid < bb + 32) atile[tid - bb] = e1 * inv;
  }
  __syncthreads();

  const float4* e = enc4 + ((long)b * T_ + base) * (H_ / 4) + tid;
  float4 acc = {0.f, 0.f, 0.f, 0.f};
  #pragma unroll 4
  for (int t = 0; t < 32; ++t) {
    float4 v = e[(long)t * (H_ / 4)];
    float at = atile[t];
    acc.x = fmaf(at, v.x, acc.x);
    acc.y = fmaf(at, v.y, acc.y);
    acc.z = fmaf(at, v.z, acc.z);
    acc.w = fmaf(at, v.w, acc.w);
  }
  part[((long)b * 16 + c) * (H_ / 4) + tid] = acc;
}

// ---- context stage 2: ctx[b][h] = sum_c partial[b][c][h]; grid 64 ----
__global__ __launch_bounds__(256) void ba_context2(const float4* __restrict__ part,
                                                   float4* __restrict__ ctx) {
  int b = blockIdx.x;
  int tid = threadIdx.x;
  const float4* p = part + (long)b * 16 * (H_ / 4) + tid;
  float4 acc = {0.f, 0.f, 0.f, 0.f};
  #pragma unroll
  for (int c = 0; c < 16; ++c) {
    float4 v = p[c * (H_ / 4)];
    acc.x += v.x; acc.y += v.y; acc.z += v.z; acc.w += v.w;
  }
  ctx[b * (H_ / 4) + tid] = acc;
}

extern "C" void kernel_launch(void* const* d_in, const int* in_sizes, int n_in,
                              void* d_out, int out_size, void* d_ws, size_t ws_size,
                              hipStream_t stream) {
  // inputs: 0 dec_hidden (unused: softmax shift-invariance), 1 enc_output,
  //         2 Wh, 3 bh, 4 Ws (unused), 5 bs (unused), 6 Wv, 7 bv (unused)
  const float* enc = (const float*)d_in[1];
  const float* Wh  = (const float*)d_in[2];
  const float* bh  = (const float*)d_in[3];
  const float* Wv  = (const float*)d_in[6];

  float* out      = (float*)d_out;
  float* ctx_out  = out;             // [64][1024]
  float* attn_out = out + B_ * H_;   // [64][512]

  char* ws = (char*)d_ws;
  u16*   encb  = (u16*)ws;                                       // 67108864 B
  u16*   whT   = (u16*)(ws + (size_t)67108864);                  //  2097152 B
  float* score = (float*)(ws + (size_t)67108864 + 2097152);      //   131072 B
  float* part  = (float*)(ws + (size_t)67108864 + 2097152 + 131072); // 4 MB

  ba_prep<<<16384 + 1024, 256, 0, stream>>>((const float4*)enc, (uint4*)encb,
                                            Wh, whT, score);
  ba_score<<<dim3(BT_ / BM, U_ / BN), 512, 0, stream>>>(encb, whT, bh, Wv, score);
  ba_context1<<<dim3(B_, 16), 256, 0, stream>>>((const float4*)enc, score,
                                                attn_out, (float4*)part);
  ba_context2<<<B_, 256, 0, stream>>>((const float4*)part, (float4*)ctx_out);
}